// Round 4
// baseline (251.218 us; speedup 1.0000x reference)
//
#include <hip/hip_runtime.h>
#include <hip/hip_bf16.h>
#include <stdint.h>

#define T_SEQ 2048
#define DIMSZ 1024
#define NH    16
#define HDIM  64
#define NBATCH 2
#define ATT_SCALE 0.12f

typedef __attribute__((ext_vector_type(8))) __bf16 bf16x8;
typedef __attribute__((ext_vector_type(4))) float f32x4;

#define GLOAD_LDS16(gp, lp)                                                            \
  __builtin_amdgcn_global_load_lds((const __attribute__((address_space(1))) void*)(gp),\
                                   (__attribute__((address_space(3))) void*)(lp),      \
                                   16, 0, 0)

__device__ __forceinline__ ushort f2bf(float f) {
  union { float f; uint32_t u; } v; v.f = f;
  uint32_t u = v.u;
  uint32_t r = (u + 0x7FFFu + ((u >> 16) & 1u)) >> 16;
  return (ushort)r;
}

// ---------------- f32 -> bf16 convert (vectorized) ----------------
__global__ __launch_bounds__(256) void conv_bf16_k(const float* __restrict__ in,
                                                   ushort* __restrict__ out, int n) {
  int i = (blockIdx.x * 256 + threadIdx.x) * 4;
  if (i >= n) return;
  float4 v = *(const float4*)(in + i);
  ushort4 o;
  o.x = f2bf(v.x); o.y = f2bf(v.y); o.z = f2bf(v.z); o.w = f2bf(v.w);
  *(ushort4*)(out + i) = o;
}

// ---------------- RoPE tables: cos/sin (T x 32) ----------------
__global__ __launch_bounds__(256) void rope_tab_k(float* __restrict__ ctab,
                                                  float* __restrict__ stab) {
  int idx = blockIdx.x * 256 + threadIdx.x;  // t*32 + j
  if (idx >= T_SEQ * 32) return;
  int j = idx & 31, t = idx >> 5;
  float c = 1.f, s = 0.f;
  if (j < 16) {
    float inv = powf(1024.0f, -(float)j / 15.0f);  // (1/1024)^(j/15)
    float th = (float)t * inv;
    c = cosf(th);
    s = sinf(th);
  }
  ctab[idx] = c;
  stab[idx] = s;
}

// ---------------- bf16 GEMM: C(MxN) = A(MxK) * Bt(NxK)^T, f32 out ----------------
#define BM 128
#define BN 128
#define BKS 64

__global__ __launch_bounds__(256) void gemm_bt_k(const ushort* __restrict__ A,
                                                 const ushort* __restrict__ Bt,
                                                 float* __restrict__ C,
                                                 int M, int N, int K) {
  __shared__ __align__(16) ushort As[BM * BKS];
  __shared__ __align__(16) ushort Bs[BN * BKS];
  int tid = threadIdx.x;
  int wave = tid >> 6, lane = tid & 63;
  int lr = lane & 15, lg = lane >> 4;
  int m0 = blockIdx.x * BM, n0 = blockIdx.y * BN;
  int wm = (wave >> 1) * 64, wn = (wave & 1) * 64;

  f32x4 acc[4][4];
  for (int m = 0; m < 4; ++m)
    for (int n = 0; n < 4; ++n)
      acc[m][n] = (f32x4){0.f, 0.f, 0.f, 0.f};

  for (int k0 = 0; k0 < K; k0 += BKS) {
#pragma unroll
    for (int it = 0; it < 4; ++it) {
      int idx = it * 256 + tid;        // 16B chunk id, 1024 total
      int row = idx >> 3;              // 8 chunks per 64-elem row
      int col = (idx & 7) * 8;
      GLOAD_LDS16(A + (size_t)(m0 + row) * K + k0 + col, &As[idx * 8]);
      GLOAD_LDS16(Bt + (size_t)(n0 + row) * K + k0 + col, &Bs[idx * 8]);
    }
    __syncthreads();
#pragma unroll
    for (int kk = 0; kk < 2; ++kk) {
      bf16x8 af[4], bf[4];
#pragma unroll
      for (int m = 0; m < 4; ++m)
        af[m] = *(const bf16x8*)&As[(wm + m * 16 + lr) * BKS + kk * 32 + lg * 8];
#pragma unroll
      for (int n = 0; n < 4; ++n)
        bf[n] = *(const bf16x8*)&Bs[(wn + n * 16 + lr) * BKS + kk * 32 + lg * 8];
#pragma unroll
      for (int m = 0; m < 4; ++m)
#pragma unroll
        for (int n = 0; n < 4; ++n)
          acc[m][n] = __builtin_amdgcn_mfma_f32_16x16x32_bf16(af[m], bf[n], acc[m][n], 0, 0, 0);
    }
    __syncthreads();
  }
#pragma unroll
  for (int m = 0; m < 4; ++m)
#pragma unroll
    for (int n = 0; n < 4; ++n)
#pragma unroll
      for (int r = 0; r < 4; ++r) {
        int row = m0 + wm + m * 16 + lg * 4 + r;
        int col = n0 + wn + n * 16 + lr;
        C[(size_t)row * N + col] = acc[m][n][r];
      }
}

// ---------------- per-(b,t,h): RMSNorm + RoPE + v-mix ----------------
// Q gets ATT_SCALE * log2(e) folded in so attention softmax runs in exp2 domain.
__global__ __launch_bounds__(256) void qkv_post_k(const float* __restrict__ QKVf,
                                                  const float* __restrict__ ve,
                                                  const float* __restrict__ lam,
                                                  const float* __restrict__ ctab,
                                                  const float* __restrict__ stab,
                                                  ushort* __restrict__ Qb,
                                                  ushort* __restrict__ Kb,
                                                  ushort* __restrict__ Vt) {
  int idx = blockIdx.x * 4 + (threadIdx.x >> 6);  // (b*T + t)*NH + h
  int lane = threadIdx.x & 63;
  int h = idx & (NH - 1);
  int bt = idx >> 4;
  int t = bt & (T_SEQ - 1);
  int b = bt >> 11;

  const float* base = QKVf + (size_t)bt * 3072 + h * HDIM + lane;
  float qv = base[0];
  float kv = base[1024];
  float vv = base[2048];

  float sq = qv * qv, sk = kv * kv, sv = vv * vv;
#pragma unroll
  for (int off = 1; off < 64; off <<= 1) {
    sq += __shfl_xor(sq, off);
    sk += __shfl_xor(sk, off);
    sv += __shfl_xor(sv, off);
  }
  qv *= rsqrtf(sq * (1.0f / 64.0f) + 1e-6f);
  kv *= rsqrtf(sk * (1.0f / 64.0f) + 1e-6f);
  vv *= rsqrtf(sv * (1.0f / 64.0f) + 1e-6f);

  int j = lane & 31;
  float c = ctab[t * 32 + j];
  float s = stab[t * 32 + j];
  float qo = __shfl_xor(qv, 32);
  float ko = __shfl_xor(kv, 32);
  float q2 = (lane < 32) ? (qv * c + qo * s) : (qv * c - qo * s);
  float k2 = (lane < 32) ? (kv * c + ko * s) : (kv * c - ko * s);
  float v2 = lam[0] * vv + lam[1] * ve[(size_t)bt * DIMSZ + h * HDIM + lane];

  q2 *= ATT_SCALE * 1.4426950408889634f;  // fold scale + log2(e) for exp2-domain softmax

  int bh = b * NH + h;
  Qb[((size_t)bh * T_SEQ + t) * HDIM + lane] = f2bf(q2);
  Kb[((size_t)bh * T_SEQ + t) * HDIM + lane] = f2bf(k2);
  Vt[((size_t)bh * HDIM + lane) * T_SEQ + t] = f2bf(v2);
}

// ---------------- flash attention (static-shift softmax, balanced grid) ----------------
// |S*scale*log2e| <= 64*0.12*1.4427 = 11.08 after RMSNorm, so exp2(S) cannot overflow:
// NO online max, NO O-rescale, NO per-iteration cross-lane ops. Lane-partial row sums
// reduce once in the epilogue.
// Grid (bh=32, jj=32): linear%8 = bh%8 (XCD L2 locality). qb from jj-quartets
// {j,15-j,16+j,31-j}: the 4 blocks a CU hosts have works summing to 66 and share bh.
__global__ __launch_bounds__(256, 4) void attn_k(const ushort* __restrict__ Q,
                                                 const ushort* __restrict__ K,
                                                 const ushort* __restrict__ Vt,
                                                 ushort* __restrict__ Y) {
  int bh = blockIdx.x;    // 0..31
  int jj = blockIdx.y;    // 0..31
  int q4 = jj >> 3, jm = jj & 7;
  int qb = (q4 == 0) ? jm : (q4 == 1) ? 15 - jm : (q4 == 2) ? 16 + jm : 31 - jm;

  int wave = threadIdx.x >> 6, lane = threadIdx.x & 63;
  int lr = lane & 15, lg = lane >> 4;
  int b = bh >> 4, h = bh & 15;

  __shared__ __align__(16) ushort Plds[4][16][72];

  const ushort* Kbh = K + (size_t)bh * T_SEQ * HDIM;
  const ushort* Vbh = Vt + (size_t)bh * HDIM * T_SEQ;

  int r0 = qb * 64 + wave * 16;
  int nkv = qb + 1;

  const ushort* Qbase = Q + ((size_t)bh * T_SEQ + r0) * HDIM;
  bf16x8 aq[2];
#pragma unroll
  for (int kk = 0; kk < 2; ++kk)
    aq[kk] = *(const bf16x8*)(Qbase + (size_t)lr * HDIM + kk * 32 + lg * 8);

  // per-lane fragment offsets (elements), advanced by uniform per-iter strides
  int koff[8], voff[8];
#pragma unroll
  for (int kk = 0; kk < 2; ++kk)
#pragma unroll
    for (int n = 0; n < 4; ++n) {
      koff[kk * 4 + n] = (n * 16 + lr) * HDIM + kk * 32 + lg * 8;
      voff[kk * 4 + n] = (n * 16 + lr) * T_SEQ + kk * 32 + lg * 8;
    }

  f32x4 o[4];
#pragma unroll
  for (int n = 0; n < 4; ++n) o[n] = (f32x4){0.f, 0.f, 0.f, 0.f};
  float lrow = 0.f;  // lane-partial sum of P over this lane's 16 keys/iter

  // preload K block 0
  bf16x8 kc[8];
#pragma unroll
  for (int i = 0; i < 8; ++i)
    kc[i] = *(const bf16x8*)(Kbh + koff[i]);

  int kbase = 0;  // element offset of NEXT K block
  int vbase = 0;
  for (int kb = 0; kb < nkv; ++kb) {
    // S^T = K . Q^T : lane holds S[q=r0+lr][key = kb*64 + n*16 + lg*4 + r]
    f32x4 s[4];
#pragma unroll
    for (int n = 0; n < 4; ++n) {
      f32x4 a = (f32x4){0.f, 0.f, 0.f, 0.f};
#pragma unroll
      for (int kk = 0; kk < 2; ++kk)
        a = __builtin_amdgcn_mfma_f32_16x16x32_bf16(kc[kk * 4 + n], aq[kk], a, 0, 0, 0);
      s[n] = a;
    }
    // branchless prefetch of next K block (last iter harmlessly reloads current)
    kbase = (kb + 1 < nkv) ? kbase + 64 * HDIM : kbase;
#pragma unroll
    for (int i = 0; i < 8; ++i)
      kc[i] = *(const bf16x8*)(Kbh + kbase + koff[i]);
    // V loads for this block; exp2/pack below hides their latency
    bf16x8 vv[8];
#pragma unroll
    for (int i = 0; i < 8; ++i)
      vv[i] = *(const bf16x8*)(Vbh + vbase + voff[i]);
    vbase += 64;

    // causal mask on the diagonal block
    if (kb == nkv - 1) {
      int qrow = r0 + lr;
      int kb0 = kb * 64 + lg * 4;
#pragma unroll
      for (int n = 0; n < 4; ++n)
#pragma unroll
        for (int r = 0; r < 4; ++r)
          if (kb0 + n * 16 + r > qrow) s[n][r] = -1e30f;
    }
    // P = exp2(S) (static shift 0; bounded by 2^11.1), lane-partial sum, pack to LDS
    float psum = 0.f;
#pragma unroll
    for (int n = 0; n < 4; ++n) {
      float p0 = exp2f(s[n][0]), p1 = exp2f(s[n][1]);
      float p2 = exp2f(s[n][2]), p3 = exp2f(s[n][3]);
      psum += (p0 + p1) + (p2 + p3);
      uint2 w;
      w.x = (uint32_t)f2bf(p0) | ((uint32_t)f2bf(p1) << 16);
      w.y = (uint32_t)f2bf(p2) | ((uint32_t)f2bf(p3) << 16);
      *(uint2*)&Plds[wave][lr][n * 16 + lg * 4] = w;
    }
    lrow += psum;
    // PV: O^T += V^T . P^T
#pragma unroll
    for (int kk = 0; kk < 2; ++kk) {
      bf16x8 ap = *(const bf16x8*)&Plds[wave][lr][kk * 32 + lg * 8];
#pragma unroll
      for (int n = 0; n < 4; ++n)
        o[n] = __builtin_amdgcn_mfma_f32_16x16x32_bf16(vv[kk * 4 + n], ap, o[n], 0, 0, 0);
    }
  }
  // epilogue: complete the row sum across lg groups, normalize, write
  lrow += __shfl_xor(lrow, 16);
  lrow += __shfl_xor(lrow, 32);
  float inv = 1.0f / lrow;
  int row = r0 + lr;
#pragma unroll
  for (int n = 0; n < 4; ++n) {
    uint2 w;
    w.x = (uint32_t)f2bf(o[n][0] * inv) | ((uint32_t)f2bf(o[n][1] * inv) << 16);
    w.y = (uint32_t)f2bf(o[n][2] * inv) | ((uint32_t)f2bf(o[n][3] * inv) << 16);
    *(uint2*)&Y[((size_t)b * T_SEQ + row) * DIMSZ + h * HDIM + n * 16 + lg * 4] = w;
  }
}

// ---------------- launch ----------------
extern "C" void kernel_launch(void* const* d_in, const int* in_sizes, int n_in,
                              void* d_out, int out_size, void* d_ws, size_t ws_size,
                              hipStream_t stream) {
  const float* x   = (const float*)d_in[0];
  const float* ve  = (const float*)d_in[1];
  const float* lam = (const float*)d_in[2];
  const float* w   = (const float*)d_in[4];  // (4, 1024, 1024)
  float* out = (float*)d_out;

  char* ws = (char*)d_ws;
  const size_t NTOK = (size_t)NBATCH * T_SEQ;          // 4096
  const size_t nX = NTOK * DIMSZ;                      // 4,194,304
  const size_t nW = 4ull * DIMSZ * DIMSZ;              // 4,194,304

  ushort* Xb   = (ushort*)(ws);                        // 8 MB
  ushort* Wb   = (ushort*)(ws + 8388608);              // 8 MB
  float*  QKVf = (float*)(ws + 16777216);              // 48 MB
  ushort* Qb   = (ushort*)(ws + 67108864);             // 8 MB
  ushort* Kb   = (ushort*)(ws + 75497472);             // 8 MB
  ushort* Vt   = (ushort*)(ws + 83886080);             // 8 MB
  ushort* Yb   = (ushort*)(ws + 92274688);             // 8 MB
  float*  ctab = (float*)(ws + 100663296);             // 256 KB
  float*  stab = (float*)(ws + 100925440);             // 256 KB

  conv_bf16_k<<<(int)(nX / 4 / 256), 256, 0, stream>>>(x, Xb, (int)nX);
  conv_bf16_k<<<(int)(nW / 4 / 256), 256, 0, stream>>>(w, Wb, (int)nW);
  rope_tab_k<<<(T_SEQ * 32) / 256, 256, 0, stream>>>(ctab, stab);

  // QKV: (4096 x 3072) = Xb (4096x1024) @ Wb[0:3072]^T
  gemm_bt_k<<<dim3(4096 / BM, 3072 / BN), 256, 0, stream>>>(Xb, Wb, QKVf, 4096, 3072, 1024);

  qkv_post_k<<<(int)(NTOK * NH / 4), 256, 0, stream>>>(QKVf, ve, lam, ctab, stab, Qb, Kb, Vt);

  attn_k<<<dim3(NBATCH * NH, 32), 256, 0, stream>>>(Qb, Kb, Vt, Yb);

  // out: (4096 x 1024) = Yb @ W3^T, f32 straight to d_out
  gemm_bt_k<<<dim3(4096 / BM, 1024 / BN), 256, 0, stream>>>(Yb, Wb + 3ull * DIMSZ * DIMSZ, out, 4096, 1024, 1024);
}